// Round 1
// baseline (2182.223 us; speedup 1.0000x reference)
//
#include <hip/hip_runtime.h>

// GCN 2-layer forward. N=50000, E=800000, IN=128, HID=128, OUT=64.
// ws layout (floats): deg[N] | dinv[N] | norm[E] | bufA[N*128] | bufB[N*128]
// bufA: h1, then relu(z1) in place. bufB: agg1; then h2 in [0,N*64), agg2 in [N*64, N*128).

#define N_NODES 50000
#define N_EDGES 800000

__global__ __launch_bounds__(256) void deg_kernel(const int* __restrict__ dst,
                                                  float* __restrict__ deg, int E) {
    int e = blockIdx.x * 256 + threadIdx.x;
    if (e < E) unsafeAtomicAdd(&deg[dst[e]], 1.0f);
}

__global__ __launch_bounds__(256) void dinv_kernel(const float* __restrict__ deg,
                                                   float* __restrict__ dinv, int N) {
    int i = blockIdx.x * 256 + threadIdx.x;
    if (i < N) dinv[i] = rsqrtf(deg[i] + 1.0f);  // deg counts in-edges; +1 self-loop
}

__global__ __launch_bounds__(256) void norm_kernel(const int* __restrict__ src,
                                                   const int* __restrict__ dst,
                                                   const float* __restrict__ dinv,
                                                   float* __restrict__ norm, int E) {
    int e = blockIdx.x * 256 + threadIdx.x;
    if (e < E) norm[e] = dinv[src[e]] * dinv[dst[e]];
}

// H[N][KOUT] = X[N][128] @ W[128][KOUT].  W staged in LDS; 4 rows x 8 cols per thread.
template <int KOUT>
__global__ __launch_bounds__(256) void gemm_kernel(const float* __restrict__ X,
                                                   const float* __restrict__ W,
                                                   float* __restrict__ H, int N) {
    constexpr int CPT = 8;            // cols per thread
    constexpr int CG = KOUT / CPT;    // col groups (16 or 8)
    constexpr int RG = 256 / CG;      // row groups (16 or 32)
    constexpr int R = 4;              // rows per thread
    constexpr int ROWS = RG * R;      // rows per block (64 or 128)
    __shared__ float Wl[128 * KOUT];

    const int tid = threadIdx.x;
    constexpr int WELEMS = 128 * KOUT;
    for (int i = tid * 4; i < WELEMS; i += 256 * 4)
        *(float4*)&Wl[i] = *(const float4*)&W[i];
    __syncthreads();

    const int cg = tid % CG;
    const int rg = tid / CG;
    const int row0 = blockIdx.x * ROWS + rg * R;

    float acc[R][CPT];
#pragma unroll
    for (int r = 0; r < R; ++r)
#pragma unroll
        for (int c = 0; c < CPT; ++c) acc[r][c] = 0.f;

    for (int k4 = 0; k4 < 32; ++k4) {
        float4 xv[R];
#pragma unroll
        for (int r = 0; r < R; ++r) {
            int row = row0 + r;
            if (row >= N) row = N - 1;  // clamp; tail rows not stored
            xv[r] = *(const float4*)&X[(long)row * 128 + k4 * 4];
        }
#pragma unroll
        for (int kk = 0; kk < 4; ++kk) {
            float4 w0 = *(const float4*)&Wl[(k4 * 4 + kk) * KOUT + cg * CPT];
            float4 w1 = *(const float4*)&Wl[(k4 * 4 + kk) * KOUT + cg * CPT + 4];
#pragma unroll
            for (int r = 0; r < R; ++r) {
                float xs = ((const float*)&xv[r])[kk];
                acc[r][0] += xs * w0.x;
                acc[r][1] += xs * w0.y;
                acc[r][2] += xs * w0.z;
                acc[r][3] += xs * w0.w;
                acc[r][4] += xs * w1.x;
                acc[r][5] += xs * w1.y;
                acc[r][6] += xs * w1.z;
                acc[r][7] += xs * w1.w;
            }
        }
    }
#pragma unroll
    for (int r = 0; r < R; ++r) {
        int row = row0 + r;
        if (row < N) {
            float4 o0 = {acc[r][0], acc[r][1], acc[r][2], acc[r][3]};
            float4 o1 = {acc[r][4], acc[r][5], acc[r][6], acc[r][7]};
            *(float4*)&H[(long)row * KOUT + cg * CPT] = o0;
            *(float4*)&H[(long)row * KOUT + cg * CPT + 4] = o1;
        }
    }
}

// agg[dst] += H[src] * norm[e].  One thread per (edge, 4 features).
template <int KOUT>
__global__ __launch_bounds__(256) void scatter_kernel(const float* __restrict__ H,
                                                      const int* __restrict__ src,
                                                      const int* __restrict__ dst,
                                                      const float* __restrict__ norm,
                                                      float* __restrict__ agg, long total) {
    constexpr int F4 = KOUT / 4;  // 32 or 16 (pow2)
    long gid = (long)blockIdx.x * 256 + threadIdx.x;
    if (gid >= total) return;
    int e = (int)(gid / F4);
    int f = (int)(gid % F4);
    int s = src[e], d = dst[e];
    float nm = norm[e];
    float4 v = *(const float4*)&H[(long)s * KOUT + f * 4];
    float* p = &agg[(long)d * KOUT + f * 4];
    unsafeAtomicAdd(p + 0, v.x * nm);
    unsafeAtomicAdd(p + 1, v.y * nm);
    unsafeAtomicAdd(p + 2, v.z * nm);
    unsafeAtomicAdd(p + 3, v.w * nm);
}

// out = agg + h * dinv^2 + bias  (optionally relu). out may alias h (elementwise).
template <int KOUT, bool RELU>
__global__ __launch_bounds__(256) void finalize_kernel(const float* __restrict__ agg,
                                                       const float* __restrict__ h,
                                                       const float* __restrict__ dinv,
                                                       const float* __restrict__ bias,
                                                       float* __restrict__ out, int N) {
    int gid = blockIdx.x * 256 + threadIdx.x;
    if (gid >= N * KOUT) return;
    int i = gid / KOUT;
    int c = gid % KOUT;
    float di = dinv[i];
    float z = agg[gid] + h[gid] * (di * di) + bias[c];
    if (RELU) z = fmaxf(z, 0.f);
    out[gid] = z;
}

extern "C" void kernel_launch(void* const* d_in, const int* in_sizes, int n_in,
                              void* d_out, int out_size, void* d_ws, size_t ws_size,
                              hipStream_t stream) {
    const float* x  = (const float*)d_in[0];
    const int*   ei = (const int*)d_in[1];
    const float* W1 = (const float*)d_in[2];
    const float* b1 = (const float*)d_in[3];
    const float* W2 = (const float*)d_in[4];
    const float* b2 = (const float*)d_in[5];
    float* out = (float*)d_out;

    const int N = in_sizes[0] / 128;   // 50000
    const int E = in_sizes[1] / 2;     // 800000
    const int* src = ei;
    const int* dst = ei + E;

    float* ws   = (float*)d_ws;
    float* deg  = ws;                       // [N]
    float* dinv = ws + N;                   // [N]
    float* nrm  = ws + 2 * N;               // [E]
    float* bufA = ws + 2 * N + E;           // [N*128]
    float* bufB = bufA + (long)N * 128;     // [N*128]
    float* h2   = bufB;                     // [N*64]
    float* agg2 = bufB + (long)N * 64;      // [N*64]

    // zero deg + agg1
    hipMemsetAsync(deg, 0, N * sizeof(float), stream);
    hipMemsetAsync(bufB, 0, (size_t)N * 128 * sizeof(float), stream);

    deg_kernel<<<(E + 255) / 256, 256, 0, stream>>>(dst, deg, E);
    dinv_kernel<<<(N + 255) / 256, 256, 0, stream>>>(deg, dinv, N);
    norm_kernel<<<(E + 255) / 256, 256, 0, stream>>>(src, dst, dinv, nrm, E);

    // layer 1: h1 = x@W1 -> bufA ; agg1 -> bufB ; relu(z1) -> bufA (in place)
    gemm_kernel<128><<<(N + 63) / 64, 256, 0, stream>>>(x, W1, bufA, N);
    {
        long total = (long)E * 32;
        scatter_kernel<128><<<(int)((total + 255) / 256), 256, 0, stream>>>(bufA, src, dst, nrm, bufB, total);
    }
    finalize_kernel<128, true><<<(N * 128 + 255) / 256, 256, 0, stream>>>(bufB, bufA, dinv, b1, bufA, N);

    // layer 2: h2 = relu1@W2 -> bufB[0:N*64] ; agg2 -> bufB[N*64:]; out
    hipMemsetAsync(agg2, 0, (size_t)N * 64 * sizeof(float), stream);
    gemm_kernel<64><<<(N + 127) / 128, 256, 0, stream>>>(bufA, W2, h2, N);
    {
        long total = (long)E * 16;
        scatter_kernel<64><<<(int)((total + 255) / 256), 256, 0, stream>>>(h2, src, dst, nrm, agg2, total);
    }
    finalize_kernel<64, false><<<(N * 64 + 255) / 256, 256, 0, stream>>>(agg2, h2, dinv, b2, out, N);
}

// Round 2
// 389.751 us; speedup vs baseline: 5.5990x; 5.5990x over previous
//
#include <hip/hip_runtime.h>

// GCN 2-layer forward, CSR-gather formulation (no fp32 atomics).
// N=50000, E=800000, IN=128, HID=128, OUT=64.
//
// ws layout: pairs[E] (float2 {src_as_float_bits, norm}) | deg/cnt int[N] |
//            rowptr int[N+1] | dinv float[N] | pad | bufA float[N*128] | bufB float[N*128]

__global__ __launch_bounds__(256) void deg_kernel(const int* __restrict__ dst,
                                                  int* __restrict__ deg, int E) {
    int e = blockIdx.x * 256 + threadIdx.x;
    if (e < E) atomicAdd(&deg[dst[e]], 1);
}

__global__ __launch_bounds__(256) void dinv_kernel(const int* __restrict__ deg,
                                                   float* __restrict__ dinv, int N) {
    int i = blockIdx.x * 256 + threadIdx.x;
    if (i < N) dinv[i] = rsqrtf((float)deg[i] + 1.0f);  // +1 self-loop
}

// Single-block exclusive scan over N ints -> rowptr[0..N] (rowptr[N]=total).
// Shuffle-based: per-wave inclusive scan, wave-sum scan by wave 0, carry across chunks.
__global__ __launch_bounds__(1024) void scan_kernel(const int* __restrict__ deg,
                                                    int* __restrict__ rowptr, int N) {
    __shared__ int wsum[16];
    __shared__ int carry_s;
    const int tid = threadIdx.x, lane = tid & 63, wid = tid >> 6;
    if (tid == 0) carry_s = 0;
    __syncthreads();
    for (int base = 0; base < N; base += 1024) {
        int idx = base + tid;
        int v = (idx < N) ? deg[idx] : 0;
        int incl = v;
#pragma unroll
        for (int off = 1; off < 64; off <<= 1) {
            int t = __shfl_up(incl, off, 64);
            if (lane >= off) incl += t;
        }
        if (lane == 63) wsum[wid] = incl;
        __syncthreads();
        if (wid == 0) {
            int s = (lane < 16) ? wsum[lane] : 0;
#pragma unroll
            for (int off = 1; off < 16; off <<= 1) {
                int t = __shfl_up(s, off, 64);
                if (lane >= off) s += t;
            }
            if (lane < 16) wsum[lane] = s;  // inclusive scan of wave sums
        }
        __syncthreads();
        int waveoff = (wid == 0) ? 0 : wsum[wid - 1];
        int carry = carry_s;
        if (idx < N) rowptr[idx] = carry + waveoff + incl - v;
        __syncthreads();
        if (tid == 1023) carry_s = carry + wsum[15];
        __syncthreads();
    }
    if (threadIdx.x == 0) rowptr[N] = carry_s;
}

// Bucket each edge into CSR order; pairs[pos] = {src (bits), dinv[s]*dinv[d]}.
__global__ __launch_bounds__(256) void fill_kernel(const int* __restrict__ src,
                                                   const int* __restrict__ dst,
                                                   const float* __restrict__ dinv,
                                                   const int* __restrict__ rowptr,
                                                   int* __restrict__ cnt,
                                                   float2* __restrict__ pairs, int E) {
    int e = blockIdx.x * 256 + threadIdx.x;
    if (e >= E) return;
    int s = src[e], d = dst[e];
    int pos = rowptr[d] + atomicAdd(&cnt[d], 1);
    float2 p;
    p.x = __int_as_float(s);
    p.y = dinv[s] * dinv[d];
    pairs[pos] = p;
}

// H[N][KOUT] = X[N][128] @ W[128][KOUT].  W staged in LDS; 4 rows x 8 cols per thread.
template <int KOUT>
__global__ __launch_bounds__(256) void gemm_kernel(const float* __restrict__ X,
                                                   const float* __restrict__ W,
                                                   float* __restrict__ H, int N) {
    constexpr int CPT = 8;
    constexpr int CG = KOUT / CPT;
    constexpr int RG = 256 / CG;
    constexpr int R = 4;
    constexpr int ROWS = RG * R;
    __shared__ float Wl[128 * KOUT];

    const int tid = threadIdx.x;
    constexpr int WELEMS = 128 * KOUT;
    for (int i = tid * 4; i < WELEMS; i += 256 * 4)
        *(float4*)&Wl[i] = *(const float4*)&W[i];
    __syncthreads();

    const int cg = tid % CG;
    const int rg = tid / CG;
    const int row0 = blockIdx.x * ROWS + rg * R;

    float acc[R][CPT];
#pragma unroll
    for (int r = 0; r < R; ++r)
#pragma unroll
        for (int c = 0; c < CPT; ++c) acc[r][c] = 0.f;

    for (int k4 = 0; k4 < 32; ++k4) {
        float4 xv[R];
#pragma unroll
        for (int r = 0; r < R; ++r) {
            int row = row0 + r;
            if (row >= N) row = N - 1;
            xv[r] = *(const float4*)&X[(long)row * 128 + k4 * 4];
        }
#pragma unroll
        for (int kk = 0; kk < 4; ++kk) {
            float4 w0 = *(const float4*)&Wl[(k4 * 4 + kk) * KOUT + cg * CPT];
            float4 w1 = *(const float4*)&Wl[(k4 * 4 + kk) * KOUT + cg * CPT + 4];
#pragma unroll
            for (int r = 0; r < R; ++r) {
                float xs = ((const float*)&xv[r])[kk];
                acc[r][0] += xs * w0.x; acc[r][1] += xs * w0.y;
                acc[r][2] += xs * w0.z; acc[r][3] += xs * w0.w;
                acc[r][4] += xs * w1.x; acc[r][5] += xs * w1.y;
                acc[r][6] += xs * w1.z; acc[r][7] += xs * w1.w;
            }
        }
    }
#pragma unroll
    for (int r = 0; r < R; ++r) {
        int row = row0 + r;
        if (row < N) {
            float4 o0 = {acc[r][0], acc[r][1], acc[r][2], acc[r][3]};
            float4 o1 = {acc[r][4], acc[r][5], acc[r][6], acc[r][7]};
            *(float4*)&H[(long)row * KOUT + cg * CPT] = o0;
            *(float4*)&H[(long)row * KOUT + cg * CPT + 4] = o1;
        }
    }
}

// One wave per node: out[node] = sum_e H[src_e]*norm_e + H[node]*dinv^2 + bias (opt relu).
template <int F, bool RELU>
__global__ __launch_bounds__(256) void gather_kernel(const float* __restrict__ H,
                                                     const int* __restrict__ rowptr,
                                                     const float2* __restrict__ pairs,
                                                     const float* __restrict__ dinv,
                                                     const float* __restrict__ bias,
                                                     float* __restrict__ out, int N) {
    const int wid = threadIdx.x >> 6;
    const int lane = threadIdx.x & 63;
    const int node = blockIdx.x * 4 + wid;
    if (node >= N) return;
    const int start = rowptr[node], end = rowptr[node + 1];

    if (F == 128) {
        const float2* H2 = (const float2*)H;
        float2 acc = {0.f, 0.f};
        int e = start;
        for (; e + 1 < end; e += 2) {
            float2 p0 = pairs[e], p1 = pairs[e + 1];
            int s0 = __float_as_int(p0.x), s1 = __float_as_int(p1.x);
            float2 h0 = H2[(long)s0 * 64 + lane];
            float2 h1 = H2[(long)s1 * 64 + lane];
            acc.x += h0.x * p0.y; acc.y += h0.y * p0.y;
            acc.x += h1.x * p1.y; acc.y += h1.y * p1.y;
        }
        if (e < end) {
            float2 p0 = pairs[e];
            int s0 = __float_as_int(p0.x);
            float2 h0 = H2[(long)s0 * 64 + lane];
            acc.x += h0.x * p0.y; acc.y += h0.y * p0.y;
        }
        float di = dinv[node];
        float d2 = di * di;
        float2 hv = H2[(long)node * 64 + lane];
        float2 bz = ((const float2*)bias)[lane];
        float zx = acc.x + hv.x * d2 + bz.x;
        float zy = acc.y + hv.y * d2 + bz.y;
        if (RELU) { zx = fmaxf(zx, 0.f); zy = fmaxf(zy, 0.f); }
        float2 o = {zx, zy};
        ((float2*)out)[(long)node * 64 + lane] = o;
    } else {  // F == 64
        float acc = 0.f;
        int e = start;
        for (; e + 1 < end; e += 2) {
            float2 p0 = pairs[e], p1 = pairs[e + 1];
            int s0 = __float_as_int(p0.x), s1 = __float_as_int(p1.x);
            float h0 = H[(long)s0 * 64 + lane];
            float h1 = H[(long)s1 * 64 + lane];
            acc += h0 * p0.y + h1 * p1.y;
        }
        if (e < end) {
            float2 p0 = pairs[e];
            acc += H[(long)__float_as_int(p0.x) * 64 + lane] * p0.y;
        }
        float di = dinv[node];
        float z = acc + H[(long)node * 64 + lane] * (di * di) + bias[lane];
        if (RELU) z = fmaxf(z, 0.f);
        out[(long)node * 64 + lane] = z;
    }
}

extern "C" void kernel_launch(void* const* d_in, const int* in_sizes, int n_in,
                              void* d_out, int out_size, void* d_ws, size_t ws_size,
                              hipStream_t stream) {
    const float* x  = (const float*)d_in[0];
    const int*   ei = (const int*)d_in[1];
    const float* W1 = (const float*)d_in[2];
    const float* b1 = (const float*)d_in[3];
    const float* W2 = (const float*)d_in[4];
    const float* b2 = (const float*)d_in[5];
    float* out = (float*)d_out;

    const int N = in_sizes[0] / 128;  // 50000
    const int E = in_sizes[1] / 2;    // 800000
    const int* src = ei;
    const int* dst = ei + E;

    // workspace carving (offsets in floats; keep bufA/bufB 16B-aligned)
    float* ws = (float*)d_ws;
    float2* pairs = (float2*)ws;                 // [E] float2, 8B aligned at base
    long off = 2L * E;
    int* deg    = (int*)(ws + off); off += N;    // reused as cursor
    int* rowptr = (int*)(ws + off); off += N + 1;
    float* dinv = ws + off;        off += N;
    off = (off + 3) & ~3L;                       // 16B align
    float* bufA = ws + off;        off += (long)N * 128;
    float* bufB = ws + off;

    // --- CSR build ---
    hipMemsetAsync(deg, 0, N * sizeof(int), stream);
    deg_kernel<<<(E + 255) / 256, 256, 0, stream>>>(dst, deg, E);
    dinv_kernel<<<(N + 255) / 256, 256, 0, stream>>>(deg, dinv, N);
    scan_kernel<<<1, 1024, 0, stream>>>(deg, rowptr, N);
    hipMemsetAsync(deg, 0, N * sizeof(int), stream);  // reuse as cursor
    fill_kernel<<<(E + 255) / 256, 256, 0, stream>>>(src, dst, dinv, rowptr, deg, pairs, E);

    // --- layer 1: h1 = x@W1 -> bufA ; z1 = relu(agg + self + b1) -> bufB ---
    gemm_kernel<128><<<(N + 63) / 64, 256, 0, stream>>>(x, W1, bufA, N);
    gather_kernel<128, true><<<(N + 3) / 4, 256, 0, stream>>>(bufA, rowptr, pairs, dinv, b1, bufB, N);

    // --- layer 2: h2 = z1@W2 -> bufA ; out = agg + self + b2 ---
    gemm_kernel<64><<<(N + 127) / 128, 256, 0, stream>>>(bufB, W2, bufA, N);
    gather_kernel<64, false><<<(N + 3) / 4, 256, 0, stream>>>(bufA, rowptr, pairs, dinv, b2, out, N);
}

// Round 3
// 297.263 us; speedup vs baseline: 7.3410x; 1.3111x over previous
//
#include <hip/hip_runtime.h>

// GCN 2-layer forward, CSR-gather, bf16 gather payloads (fp32 accumulate).
// N=50000, E=800000, IN=128, HID=128, OUT=64.

typedef unsigned short ushort_t;
typedef unsigned int uint_t;

__device__ __forceinline__ float bf2f(uint_t u) { return __uint_as_float(u << 16); }
__device__ __forceinline__ ushort_t f2bf(float f) {
    uint_t u = __float_as_uint(f);
    u += 0x7FFFu + ((u >> 16) & 1u);
    return (ushort_t)(u >> 16);
}

__global__ __launch_bounds__(256) void deg_kernel(const int* __restrict__ dst,
                                                  int* __restrict__ deg, int E) {
    int e = blockIdx.x * 256 + threadIdx.x;
    if (e < E) atomicAdd(&deg[dst[e]], 1);
}

// Per-block exclusive scan (block=1024). Writes excl-in-block to rowptr, block sum
// to bsum, and dinv = rsqrt(deg+1) on the side.
__global__ __launch_bounds__(1024) void scan1_kernel(const int* __restrict__ deg,
                                                     int* __restrict__ rowptr,
                                                     int* __restrict__ bsum,
                                                     float* __restrict__ dinv, int N) {
    __shared__ int wsum[16];
    const int tid = threadIdx.x, lane = tid & 63, wid = tid >> 6;
    const int idx = blockIdx.x * 1024 + tid;
    int v = (idx < N) ? deg[idx] : 0;
    if (idx < N) dinv[idx] = rsqrtf((float)v + 1.0f);
    int incl = v;
#pragma unroll
    for (int off = 1; off < 64; off <<= 1) {
        int t = __shfl_up(incl, off, 64);
        if (lane >= off) incl += t;
    }
    if (lane == 63) wsum[wid] = incl;
    __syncthreads();
    if (wid == 0) {
        int s = (lane < 16) ? wsum[lane] : 0;
#pragma unroll
        for (int off = 1; off < 16; off <<= 1) {
            int t = __shfl_up(s, off, 64);
            if (lane >= off) s += t;
        }
        if (lane < 16) wsum[lane] = s;
    }
    __syncthreads();
    int waveoff = (wid == 0) ? 0 : wsum[wid - 1];
    if (idx < N) rowptr[idx] = waveoff + incl - v;
    if (tid == 1023) bsum[blockIdx.x] = waveoff + incl;
}

// Inclusive scan of <=64 block sums, one wave.
__global__ __launch_bounds__(64) void scan2_kernel(int* __restrict__ bsum, int nb) {
    int lane = threadIdx.x;
    int v = (lane < nb) ? bsum[lane] : 0;
    int incl = v;
#pragma unroll
    for (int off = 1; off < 64; off <<= 1) {
        int t = __shfl_up(incl, off, 64);
        if (lane >= off) incl += t;
    }
    if (lane < nb) bsum[lane] = incl;
}

__global__ __launch_bounds__(1024) void scan3_kernel(int* __restrict__ rowptr,
                                                     const int* __restrict__ bsum,
                                                     int N, int nb) {
    int idx = blockIdx.x * 1024 + threadIdx.x;
    if (blockIdx.x > 0 && idx < N) rowptr[idx] += bsum[blockIdx.x - 1];
    if (idx == 0) rowptr[N] = bsum[nb - 1];
}

__global__ __launch_bounds__(256) void fill_kernel(const int* __restrict__ src,
                                                   const int* __restrict__ dst,
                                                   const float* __restrict__ dinv,
                                                   const int* __restrict__ rowptr,
                                                   int* __restrict__ cnt,
                                                   float2* __restrict__ pairs, int E) {
    int e = blockIdx.x * 256 + threadIdx.x;
    if (e >= E) return;
    int s = src[e], d = dst[e];
    int pos = rowptr[d] + atomicAdd(&cnt[d], 1);
    float2 p;
    p.x = __int_as_float(s);
    p.y = dinv[s] * dinv[d];
    pairs[pos] = p;
}

// H[N][KOUT] = X[N][128] @ W[128][KOUT], output stored as bf16 (ushort).
template <int KOUT>
__global__ __launch_bounds__(256) void gemm_kernel(const float* __restrict__ X,
                                                   const float* __restrict__ W,
                                                   ushort_t* __restrict__ H, int N) {
    constexpr int CPT = 8;
    constexpr int CG = KOUT / CPT;
    constexpr int RG = 256 / CG;
    constexpr int R = 4;
    constexpr int ROWS = RG * R;
    __shared__ float Wl[128 * KOUT];

    const int tid = threadIdx.x;
    constexpr int WELEMS = 128 * KOUT;
    for (int i = tid * 4; i < WELEMS; i += 256 * 4)
        *(float4*)&Wl[i] = *(const float4*)&W[i];
    __syncthreads();

    const int cg = tid % CG;
    const int rg = tid / CG;
    const int row0 = blockIdx.x * ROWS + rg * R;

    float acc[R][CPT];
#pragma unroll
    for (int r = 0; r < R; ++r)
#pragma unroll
        for (int c = 0; c < CPT; ++c) acc[r][c] = 0.f;

    for (int k4 = 0; k4 < 32; ++k4) {
        float4 xv[R];
#pragma unroll
        for (int r = 0; r < R; ++r) {
            int row = row0 + r;
            if (row >= N) row = N - 1;
            xv[r] = *(const float4*)&X[(long)row * 128 + k4 * 4];
        }
#pragma unroll
        for (int kk = 0; kk < 4; ++kk) {
            float4 w0 = *(const float4*)&Wl[(k4 * 4 + kk) * KOUT + cg * CPT];
            float4 w1 = *(const float4*)&Wl[(k4 * 4 + kk) * KOUT + cg * CPT + 4];
#pragma unroll
            for (int r = 0; r < R; ++r) {
                float xs = ((const float*)&xv[r])[kk];
                acc[r][0] += xs * w0.x; acc[r][1] += xs * w0.y;
                acc[r][2] += xs * w0.z; acc[r][3] += xs * w0.w;
                acc[r][4] += xs * w1.x; acc[r][5] += xs * w1.y;
                acc[r][6] += xs * w1.z; acc[r][7] += xs * w1.w;
            }
        }
    }
#pragma unroll
    for (int r = 0; r < R; ++r) {
        int row = row0 + r;
        if (row < N) {
            ushort_t tmp[8];
#pragma unroll
            for (int c = 0; c < 8; ++c) tmp[c] = f2bf(acc[r][c]);
            *(uint4*)&H[(long)row * KOUT + cg * CPT] = *(uint4*)tmp;
        }
    }
}

// One wave per node. F=128: lane reads a packed bf16 pair (uint) per edge.
template <int F, bool RELU>
__global__ __launch_bounds__(256) void gather_kernel(const ushort_t* __restrict__ H,
                                                     const int* __restrict__ rowptr,
                                                     const float2* __restrict__ pairs,
                                                     const float* __restrict__ dinv,
                                                     const float* __restrict__ bias,
                                                     float* __restrict__ out, int N) {
    const int wid = threadIdx.x >> 6;
    const int lane = threadIdx.x & 63;
    const int node = blockIdx.x * 4 + wid;
    if (node >= N) return;
    const int start = rowptr[node], end = rowptr[node + 1];

    if (F == 128) {
        const uint_t* Hu = (const uint_t*)H;  // 64 uints per row
        float ax = 0.f, ay = 0.f;
        int e = start;
        for (; e + 3 < end; e += 4) {
            float2 p0 = pairs[e], p1 = pairs[e + 1], p2 = pairs[e + 2], p3 = pairs[e + 3];
            uint_t u0 = Hu[(long)__float_as_int(p0.x) * 64 + lane];
            uint_t u1 = Hu[(long)__float_as_int(p1.x) * 64 + lane];
            uint_t u2 = Hu[(long)__float_as_int(p2.x) * 64 + lane];
            uint_t u3 = Hu[(long)__float_as_int(p3.x) * 64 + lane];
            ax += bf2f(u0 & 0xFFFFu) * p0.y; ay += __uint_as_float(u0 & 0xFFFF0000u) * p0.y;
            ax += bf2f(u1 & 0xFFFFu) * p1.y; ay += __uint_as_float(u1 & 0xFFFF0000u) * p1.y;
            ax += bf2f(u2 & 0xFFFFu) * p2.y; ay += __uint_as_float(u2 & 0xFFFF0000u) * p2.y;
            ax += bf2f(u3 & 0xFFFFu) * p3.y; ay += __uint_as_float(u3 & 0xFFFF0000u) * p3.y;
        }
        for (; e < end; ++e) {
            float2 p0 = pairs[e];
            uint_t u0 = Hu[(long)__float_as_int(p0.x) * 64 + lane];
            ax += bf2f(u0 & 0xFFFFu) * p0.y; ay += __uint_as_float(u0 & 0xFFFF0000u) * p0.y;
        }
        float di = dinv[node];
        float d2 = di * di;
        uint_t us = Hu[(long)node * 64 + lane];
        float2 bz = ((const float2*)bias)[lane];
        float zx = ax + bf2f(us & 0xFFFFu) * d2 + bz.x;
        float zy = ay + __uint_as_float(us & 0xFFFF0000u) * d2 + bz.y;
        if (RELU) { zx = fmaxf(zx, 0.f); zy = fmaxf(zy, 0.f); }
        float2 o = {zx, zy};
        ((float2*)out)[(long)node * 64 + lane] = o;
    } else {  // F == 64
        float acc = 0.f;
        int e = start;
        for (; e + 3 < end; e += 4) {
            float2 p0 = pairs[e], p1 = pairs[e + 1], p2 = pairs[e + 2], p3 = pairs[e + 3];
            ushort_t u0 = H[(long)__float_as_int(p0.x) * 64 + lane];
            ushort_t u1 = H[(long)__float_as_int(p1.x) * 64 + lane];
            ushort_t u2 = H[(long)__float_as_int(p2.x) * 64 + lane];
            ushort_t u3 = H[(long)__float_as_int(p3.x) * 64 + lane];
            acc += bf2f(u0) * p0.y + bf2f(u1) * p1.y + bf2f(u2) * p2.y + bf2f(u3) * p3.y;
        }
        for (; e < end; ++e) {
            float2 p0 = pairs[e];
            acc += bf2f(H[(long)__float_as_int(p0.x) * 64 + lane]) * p0.y;
        }
        float di = dinv[node];
        float z = acc + bf2f(H[(long)node * 64 + lane]) * (di * di) + bias[lane];
        if (RELU) z = fmaxf(z, 0.f);
        out[(long)node * 64 + lane] = z;
    }
}

extern "C" void kernel_launch(void* const* d_in, const int* in_sizes, int n_in,
                              void* d_out, int out_size, void* d_ws, size_t ws_size,
                              hipStream_t stream) {
    const float* x  = (const float*)d_in[0];
    const int*   ei = (const int*)d_in[1];
    const float* W1 = (const float*)d_in[2];
    const float* b1 = (const float*)d_in[3];
    const float* W2 = (const float*)d_in[4];
    const float* b2 = (const float*)d_in[5];
    float* out = (float*)d_out;

    const int N = in_sizes[0] / 128;  // 50000
    const int E = in_sizes[1] / 2;    // 800000
    const int* src = ei;
    const int* dst = ei + E;
    const int NB = (N + 1023) / 1024;  // 49

    // workspace carving (float-offset units; all sub-buffers 16B aligned enough)
    float* ws = (float*)d_ws;
    float2* pairs = (float2*)ws;                  // [E] float2
    long off = 2L * E;
    int* deg    = (int*)(ws + off); off += N;     // counter
    int* cnt    = (int*)(ws + off); off += N;     // fill cursor (zeroed together with deg)
    int* rowptr = (int*)(ws + off); off += N + 1;
    int* bsum   = (int*)(ws + off); off += 64;
    float* dinv = ws + off;        off += N;
    off = (off + 3) & ~3L;
    ushort_t* h1 = (ushort_t*)(ws + off); off += (long)N * 64;   // N*128 bf16
    float* z1    = ws + off;              off += (long)N * 128;  // fp32
    ushort_t* h2 = (ushort_t*)(ws + off); off += (long)N * 32;   // N*64 bf16

    // --- CSR build ---
    hipMemsetAsync(deg, 0, 2L * N * sizeof(int), stream);  // deg + cnt
    deg_kernel<<<(E + 255) / 256, 256, 0, stream>>>(dst, deg, E);
    scan1_kernel<<<NB, 1024, 0, stream>>>(deg, rowptr, bsum, dinv, N);
    scan2_kernel<<<1, 64, 0, stream>>>(bsum, NB);
    scan3_kernel<<<NB, 1024, 0, stream>>>(rowptr, bsum, N, NB);
    fill_kernel<<<(E + 255) / 256, 256, 0, stream>>>(src, dst, dinv, rowptr, cnt, pairs, E);

    // --- layer 1 ---
    gemm_kernel<128><<<(N + 63) / 64, 256, 0, stream>>>(x, W1, h1, N);
    gather_kernel<128, true><<<(N + 3) / 4, 256, 0, stream>>>(h1, rowptr, pairs, dinv, b1, z1, N);

    // --- layer 2 ---
    gemm_kernel<64><<<(N + 127) / 128, 256, 0, stream>>>(z1, W2, h2, N);
    gather_kernel<64, false><<<(N + 3) / 4, 256, 0, stream>>>(h2, rowptr, pairs, dinv, b2, out, N);
}

// Round 5
// 262.512 us; speedup vs baseline: 8.3128x; 1.1324x over previous
//
#include <hip/hip_runtime.h>
#include <hip/hip_fp16.h>

// GCN 2-layer forward: CSR-gather + fp16-MFMA GEMMs (fp32 accumulate).
// N=50000, E=800000, IN=128, HID=128, OUT=64.

typedef _Float16 f16;
typedef __attribute__((ext_vector_type(8))) _Float16 f16x8;
typedef __attribute__((ext_vector_type(4))) float f32x4;

__global__ __launch_bounds__(256) void deg_kernel(const int* __restrict__ dst,
                                                  int* __restrict__ deg, int E) {
    int e = blockIdx.x * 256 + threadIdx.x;
    if (e < E) atomicAdd(&deg[dst[e]], 1);
}

// Per-block exclusive scan (block=1024); block sums to bsum; dinv on the side.
__global__ __launch_bounds__(1024) void scan1_kernel(const int* __restrict__ deg,
                                                     int* __restrict__ rowptr,
                                                     int* __restrict__ bsum,
                                                     float* __restrict__ dinv, int N) {
    __shared__ int wsum[16];
    const int tid = threadIdx.x, lane = tid & 63, wid = tid >> 6;
    const int idx = blockIdx.x * 1024 + tid;
    int v = (idx < N) ? deg[idx] : 0;
    if (idx < N) dinv[idx] = rsqrtf((float)v + 1.0f);
    int incl = v;
#pragma unroll
    for (int off = 1; off < 64; off <<= 1) {
        int t = __shfl_up(incl, off, 64);
        if (lane >= off) incl += t;
    }
    if (lane == 63) wsum[wid] = incl;
    __syncthreads();
    if (wid == 0) {
        int s = (lane < 16) ? wsum[lane] : 0;
#pragma unroll
        for (int off = 1; off < 16; off <<= 1) {
            int t = __shfl_up(s, off, 64);
            if (lane >= off) s += t;
        }
        if (lane < 16) wsum[lane] = s;
    }
    __syncthreads();
    int waveoff = (wid == 0) ? 0 : wsum[wid - 1];
    if (idx < N) rowptr[idx] = waveoff + incl - v;
    if (tid == 1023) bsum[blockIdx.x] = waveoff + incl;
}

__global__ __launch_bounds__(64) void scan2_kernel(int* __restrict__ bsum, int nb) {
    int lane = threadIdx.x;
    int v = (lane < nb) ? bsum[lane] : 0;
    int incl = v;
#pragma unroll
    for (int off = 1; off < 64; off <<= 1) {
        int t = __shfl_up(incl, off, 64);
        if (lane >= off) incl += t;
    }
    if (lane < nb) bsum[lane] = incl;
}

__global__ __launch_bounds__(1024) void scan3_kernel(int* __restrict__ rowptr,
                                                     const int* __restrict__ bsum,
                                                     int N, int nb) {
    int idx = blockIdx.x * 1024 + threadIdx.x;
    if (blockIdx.x > 0 && idx < N) rowptr[idx] += bsum[blockIdx.x - 1];
    if (idx == 0) rowptr[N] = bsum[nb - 1];
}

__global__ __launch_bounds__(256) void fill_kernel(const int* __restrict__ src,
                                                   const int* __restrict__ dst,
                                                   const float* __restrict__ dinv,
                                                   const int* __restrict__ rowptr,
                                                   int* __restrict__ cnt,
                                                   float2* __restrict__ pairs, int E) {
    int e = blockIdx.x * 256 + threadIdx.x;
    if (e >= E) return;
    int s = src[e], d = dst[e];
    int pos = rowptr[d] + atomicAdd(&cnt[d], 1);
    float2 p;
    p.x = __int_as_float(s);
    p.y = dinv[s] * dinv[d];
    pairs[pos] = p;
}

// W[k][c] fp32 -> Wt[c][k] fp16, k-contiguous, row stride 136 halves (pad 8).
__global__ __launch_bounds__(256) void prep_w(const float* __restrict__ W1,
                                              const float* __restrict__ W2,
                                              f16* __restrict__ Wt1, f16* __restrict__ Wt2) {
    int i = blockIdx.x * 256 + threadIdx.x;
    if (i < 128 * 128) {
        int k = i >> 7, c = i & 127;
        Wt1[c * 136 + k] = (f16)W1[i];
    } else if (i < 128 * 128 + 128 * 64) {
        int j = i - 128 * 128;
        int k = j >> 6, c = j & 63;
        Wt2[c * 136 + k] = (f16)W2[j];
    }
}

// H[N][KOUT](fp16) = X[N][128] @ W[128][KOUT] via mfma_f32_16x16x32_f16.
// Block: 256 thr = 4 waves x 16 rows. Wt (pre-transposed fp16) staged to LDS.
template <int KOUT, bool F32IN>
__global__ __launch_bounds__(256) void gemm_kernel(const void* __restrict__ Xv,
                                                   const f16* __restrict__ Wt,
                                                   f16* __restrict__ H, int N) {
    constexpr int CT = KOUT / 16;
    __shared__ f16 Wl[KOUT * 136];
    const int tid = threadIdx.x;
    constexpr int CHUNKS = KOUT * 136 / 8;  // 16B chunks
    {
        const uint4* s = (const uint4*)Wt;
        uint4* d = (uint4*)Wl;
        for (int i = tid; i < CHUNKS; i += 256) d[i] = s[i];
    }
    __syncthreads();

    const int lane = tid & 63, wid = tid >> 6;
    const int c = lane & 15, kseg = lane >> 4;
    const int row0 = blockIdx.x * 64 + wid * 16;
    int arow = row0 + c;
    if (arow >= N) arow = N - 1;  // clamp; stores guarded

    f32x4 acc[CT];
#pragma unroll
    for (int t = 0; t < CT; ++t) acc[t] = (f32x4){0.f, 0.f, 0.f, 0.f};

#pragma unroll
    for (int kt = 0; kt < 4; ++kt) {
        const int k0 = kt * 32;
        f16x8 a;
        if (F32IN) {
            const float* xp = (const float*)Xv + (long)arow * 128 + k0 + kseg * 8;
            float4 x0 = *(const float4*)xp;
            float4 x1 = *(const float4*)(xp + 4);
            a[0] = (f16)x0.x; a[1] = (f16)x0.y; a[2] = (f16)x0.z; a[3] = (f16)x0.w;
            a[4] = (f16)x1.x; a[5] = (f16)x1.y; a[6] = (f16)x1.z; a[7] = (f16)x1.w;
        } else {
            a = *(const f16x8*)((const f16*)Xv + (long)arow * 128 + k0 + kseg * 8);
        }
#pragma unroll
        for (int ct = 0; ct < CT; ++ct) {
            f16x8 b = *(const f16x8*)&Wl[(ct * 16 + c) * 136 + k0 + kseg * 8];
            acc[ct] = __builtin_amdgcn_mfma_f32_16x16x32_f16(a, b, acc[ct], 0, 0, 0);
        }
    }

    // C/D: col = lane&15, row(in tile) = (lane>>4)*4 + reg  [HW-verified layout]
    const int rbase = row0 + kseg * 4;
#pragma unroll
    for (int ct = 0; ct < CT; ++ct)
#pragma unroll
        for (int r = 0; r < 4; ++r) {
            int row = rbase + r;
            if (row < N) H[(long)row * KOUT + ct * 16 + c] = (f16)acc[ct][r];
        }
}

// One wave per node; fp16 payloads, fp32 accumulate; fused self-loop+bias(+relu).
template <int F, bool RELU, bool OUTF16>
__global__ __launch_bounds__(256) void gather_kernel(const void* __restrict__ Hv,
                                                     const int* __restrict__ rowptr,
                                                     const float2* __restrict__ pairs,
                                                     const float* __restrict__ dinv,
                                                     const float* __restrict__ bias,
                                                     void* __restrict__ outv, int N) {
    const int wid = threadIdx.x >> 6;
    const int lane = threadIdx.x & 63;
    const int node = blockIdx.x * 4 + wid;
    if (node >= N) return;
    const int start = rowptr[node], end = rowptr[node + 1];

    if (F == 128) {
        const __half2* Hu = (const __half2*)Hv;  // 64 half2 per row
        float ax = 0.f, ay = 0.f;
        int e = start;
        for (; e + 3 < end; e += 4) {
            float2 p0 = pairs[e], p1 = pairs[e + 1], p2 = pairs[e + 2], p3 = pairs[e + 3];
            __half2 u0 = Hu[(long)__float_as_int(p0.x) * 64 + lane];
            __half2 u1 = Hu[(long)__float_as_int(p1.x) * 64 + lane];
            __half2 u2 = Hu[(long)__float_as_int(p2.x) * 64 + lane];
            __half2 u3 = Hu[(long)__float_as_int(p3.x) * 64 + lane];
            float2 f0 = __half22float2(u0), f1 = __half22float2(u1);
            float2 f2 = __half22float2(u2), f3 = __half22float2(u3);
            ax += f0.x * p0.y + f1.x * p1.y + f2.x * p2.y + f3.x * p3.y;
            ay += f0.y * p0.y + f1.y * p1.y + f2.y * p2.y + f3.y * p3.y;
        }
        for (; e < end; ++e) {
            float2 p0 = pairs[e];
            float2 f0 = __half22float2(Hu[(long)__float_as_int(p0.x) * 64 + lane]);
            ax += f0.x * p0.y;
            ay += f0.y * p0.y;
        }
        float di = dinv[node];
        float d2 = di * di;
        float2 fs = __half22float2(Hu[(long)node * 64 + lane]);
        float2 bz = ((const float2*)bias)[lane];
        float zx = ax + fs.x * d2 + bz.x;
        float zy = ay + fs.y * d2 + bz.y;
        if (RELU) { zx = fmaxf(zx, 0.f); zy = fmaxf(zy, 0.f); }
        if (OUTF16) {
            ((__half2*)outv)[(long)node * 64 + lane] = __float22half2_rn(make_float2(zx, zy));
        } else {
            float2 o = {zx, zy};
            ((float2*)outv)[(long)node * 64 + lane] = o;
        }
    } else {  // F == 64
        const __half* Hh = (const __half*)Hv;
        float acc = 0.f;
        int e = start;
        for (; e + 3 < end; e += 4) {
            float2 p0 = pairs[e], p1 = pairs[e + 1], p2 = pairs[e + 2], p3 = pairs[e + 3];
            float h0 = __half2float(Hh[(long)__float_as_int(p0.x) * 64 + lane]);
            float h1 = __half2float(Hh[(long)__float_as_int(p1.x) * 64 + lane]);
            float h2 = __half2float(Hh[(long)__float_as_int(p2.x) * 64 + lane]);
            float h3 = __half2float(Hh[(long)__float_as_int(p3.x) * 64 + lane]);
            acc += h0 * p0.y + h1 * p1.y + h2 * p2.y + h3 * p3.y;
        }
        for (; e < end; ++e) {
            float2 p0 = pairs[e];
            acc += __half2float(Hh[(long)__float_as_int(p0.x) * 64 + lane]) * p0.y;
        }
        float di = dinv[node];
        float z = acc + __half2float(Hh[(long)node * 64 + lane]) * (di * di) + bias[lane];
        if (RELU) z = fmaxf(z, 0.f);
        ((float*)outv)[(long)node * 64 + lane] = z;
    }
}

extern "C" void kernel_launch(void* const* d_in, const int* in_sizes, int n_in,
                              void* d_out, int out_size, void* d_ws, size_t ws_size,
                              hipStream_t stream) {
    const float* x  = (const float*)d_in[0];
    const int*   ei = (const int*)d_in[1];
    const float* W1 = (const float*)d_in[2];
    const float* b1 = (const float*)d_in[3];
    const float* W2 = (const float*)d_in[4];
    const float* b2 = (const float*)d_in[5];
    float* out = (float*)d_out;

    const int N = in_sizes[0] / 128;  // 50000
    const int E = in_sizes[1] / 2;    // 800000
    const int* src = ei;
    const int* dst = ei + E;
    const int NB = (N + 1023) / 1024;  // 49

    // workspace carving (float units; fp16 buffers 16B-aligned)
    float* ws = (float*)d_ws;
    float2* pairs = (float2*)ws;                  // [E]
    long off = 2L * E;
    int* deg    = (int*)(ws + off); off += N;
    int* cnt    = (int*)(ws + off); off += N;
    int* rowptr = (int*)(ws + off); off += N + 1;
    int* bsum   = (int*)(ws + off); off += 64;
    float* dinv = ws + off;        off += N;
    off = (off + 3) & ~3L;
    f16* Wt1 = (f16*)(ws + off); off += (128 * 136) / 2;   // fp16
    f16* Wt2 = (f16*)(ws + off); off += (64 * 136) / 2;
    f16* h1  = (f16*)(ws + off); off += (long)N * 64;      // N*128 fp16
    f16* z1  = (f16*)(ws + off); off += (long)N * 64;      // N*128 fp16
    f16* h2  = (f16*)(ws + off); off += (long)N * 32;      // N*64 fp16

    // --- CSR build + weight prep ---
    hipMemsetAsync(deg, 0, 2L * N * sizeof(int), stream);  // deg + cnt
    prep_w<<<(128 * 128 + 128 * 64 + 255) / 256, 256, 0, stream>>>(W1, W2, Wt1, Wt2);
    deg_kernel<<<(E + 255) / 256, 256, 0, stream>>>(dst, deg, E);
    scan1_kernel<<<NB, 1024, 0, stream>>>(deg, rowptr, bsum, dinv, N);
    scan2_kernel<<<1, 64, 0, stream>>>(bsum, NB);
    scan3_kernel<<<NB, 1024, 0, stream>>>(rowptr, bsum, N, NB);
    fill_kernel<<<(E + 255) / 256, 256, 0, stream>>>(src, dst, dinv, rowptr, cnt, pairs, E);

    // --- layer 1: h1 = f16(x@W1); z1 = f16(relu(agg + self + b1)) ---
    gemm_kernel<128, true><<<(N + 63) / 64, 256, 0, stream>>>(x, Wt1, h1, N);
    gather_kernel<128, true, true><<<(N + 3) / 4, 256, 0, stream>>>(h1, rowptr, pairs, dinv, b1, z1, N);

    // --- layer 2: h2 = f16(z1@W2); out = agg + self + b2 (fp32) ---
    gemm_kernel<64, false><<<(N + 63) / 64, 256, 0, stream>>>(z1, Wt2, h2, N);
    gather_kernel<64, false, false><<<(N + 3) / 4, 256, 0, stream>>>(h2, rowptr, pairs, dinv, b2, out, N);
}

// Round 6
// 228.201 us; speedup vs baseline: 9.5627x; 1.1504x over previous
//
#include <hip/hip_runtime.h>
#include <hip/hip_fp16.h>

// GCN 2-layer forward: CSR-gather + fp16-MFMA GEMMs (fp32 accumulate).
// N=50000, E=800000, IN=128, HID=128, OUT=64.
// R6: atomic-free fill (posw captured in deg pass), merged scans, 8-wide gather unroll.

typedef _Float16 f16;
typedef __attribute__((ext_vector_type(8))) _Float16 f16x8;
typedef __attribute__((ext_vector_type(4))) float f32x4;

// Pass 1: deg histogram + per-edge within-row position; first blocks also
// transpose W1/W2 to fp16 k-contiguous (stride 136).
__global__ __launch_bounds__(256) void deg_prep_kernel(const int* __restrict__ dst,
                                                       int* __restrict__ deg,
                                                       int* __restrict__ posw,
                                                       const float* __restrict__ W1,
                                                       const float* __restrict__ W2,
                                                       f16* __restrict__ Wt1,
                                                       f16* __restrict__ Wt2, int E) {
    int gid = blockIdx.x * 256 + threadIdx.x;
    if (gid < E) posw[gid] = atomicAdd(&deg[dst[gid]], 1);
    if (gid < 128 * 128) {
        int k = gid >> 7, c = gid & 127;
        Wt1[c * 136 + k] = (f16)W1[gid];
    } else if (gid < 128 * 128 + 128 * 64) {
        int j = gid - 128 * 128;
        int k = j >> 6, c = j & 63;
        Wt2[c * 136 + k] = (f16)W2[j];
    }
}

// Per-block exclusive scan (block=1024); block sums to bsum; dinv on the side.
__global__ __launch_bounds__(1024) void scan1_kernel(const int* __restrict__ deg,
                                                     int* __restrict__ rowptr,
                                                     int* __restrict__ bsum,
                                                     float* __restrict__ dinv, int N) {
    __shared__ int wsum[16];
    const int tid = threadIdx.x, lane = tid & 63, wid = tid >> 6;
    const int idx = blockIdx.x * 1024 + tid;
    int v = (idx < N) ? deg[idx] : 0;
    if (idx < N) dinv[idx] = rsqrtf((float)v + 1.0f);
    int incl = v;
#pragma unroll
    for (int off = 1; off < 64; off <<= 1) {
        int t = __shfl_up(incl, off, 64);
        if (lane >= off) incl += t;
    }
    if (lane == 63) wsum[wid] = incl;
    __syncthreads();
    if (wid == 0) {
        int s = (lane < 16) ? wsum[lane] : 0;
#pragma unroll
        for (int off = 1; off < 16; off <<= 1) {
            int t = __shfl_up(s, off, 64);
            if (lane >= off) s += t;
        }
        if (lane < 16) wsum[lane] = s;
    }
    __syncthreads();
    int waveoff = (wid == 0) ? 0 : wsum[wid - 1];
    if (idx < N) rowptr[idx] = waveoff + incl - v;
    if (tid == 1023) bsum[blockIdx.x] = waveoff + incl;
}

// Merged scan2+scan3: each block wave-reduces its exclusive prefix of bsum
// (nb <= 64) and adds it; block 0 also writes rowptr[N] = total.
__global__ __launch_bounds__(1024) void scan23_kernel(int* __restrict__ rowptr,
                                                      const int* __restrict__ bsum,
                                                      int N, int nb) {
    __shared__ int pfx_s;
    const int tid = threadIdx.x;
    if (tid < 64) {
        int v = (tid < nb && tid < blockIdx.x) ? bsum[tid] : 0;
#pragma unroll
        for (int off = 32; off; off >>= 1) v += __shfl_xor(v, off, 64);
        if (tid == 0) pfx_s = v;
    }
    if (blockIdx.x == 0 && tid >= 64 && tid < 128) {
        int l = tid - 64;
        int v = (l < nb) ? bsum[l] : 0;
#pragma unroll
        for (int off = 32; off; off >>= 1) v += __shfl_xor(v, off, 64);
        if (l == 0) rowptr[N] = v;
    }
    __syncthreads();
    int idx = blockIdx.x * 1024 + tid;
    if (idx < N) rowptr[idx] += pfx_s;
}

// Atomic-free CSR fill: pos = rowptr[dst] + posw.
__global__ __launch_bounds__(256) void fill_kernel(const int* __restrict__ src,
                                                   const int* __restrict__ dst,
                                                   const int* __restrict__ posw,
                                                   const float* __restrict__ dinv,
                                                   const int* __restrict__ rowptr,
                                                   float2* __restrict__ pairs, int E) {
    int e = blockIdx.x * 256 + threadIdx.x;
    if (e >= E) return;
    int s = src[e], d = dst[e];
    float2 p;
    p.x = __int_as_float(s);
    p.y = dinv[s] * dinv[d];
    pairs[rowptr[d] + posw[e]] = p;
}

// H[N][KOUT](fp16) = X[N][128] @ W[128][KOUT] via mfma_f32_16x16x32_f16.
template <int KOUT, bool F32IN>
__global__ __launch_bounds__(256) void gemm_kernel(const void* __restrict__ Xv,
                                                   const f16* __restrict__ Wt,
                                                   f16* __restrict__ H, int N) {
    constexpr int CT = KOUT / 16;
    __shared__ f16 Wl[KOUT * 136];
    const int tid = threadIdx.x;
    constexpr int CHUNKS = KOUT * 136 / 8;
    {
        const uint4* s = (const uint4*)Wt;
        uint4* d = (uint4*)Wl;
        for (int i = tid; i < CHUNKS; i += 256) d[i] = s[i];
    }
    __syncthreads();

    const int lane = tid & 63, wid = tid >> 6;
    const int c = lane & 15, kseg = lane >> 4;
    const int row0 = blockIdx.x * 64 + wid * 16;
    int arow = row0 + c;
    if (arow >= N) arow = N - 1;

    f32x4 acc[CT];
#pragma unroll
    for (int t = 0; t < CT; ++t) acc[t] = (f32x4){0.f, 0.f, 0.f, 0.f};

#pragma unroll
    for (int kt = 0; kt < 4; ++kt) {
        const int k0 = kt * 32;
        f16x8 a;
        if (F32IN) {
            const float* xp = (const float*)Xv + (long)arow * 128 + k0 + kseg * 8;
            float4 x0 = *(const float4*)xp;
            float4 x1 = *(const float4*)(xp + 4);
            a[0] = (f16)x0.x; a[1] = (f16)x0.y; a[2] = (f16)x0.z; a[3] = (f16)x0.w;
            a[4] = (f16)x1.x; a[5] = (f16)x1.y; a[6] = (f16)x1.z; a[7] = (f16)x1.w;
        } else {
            a = *(const f16x8*)((const f16*)Xv + (long)arow * 128 + k0 + kseg * 8);
        }
#pragma unroll
        for (int ct = 0; ct < CT; ++ct) {
            f16x8 b = *(const f16x8*)&Wl[(ct * 16 + c) * 136 + k0 + kseg * 8];
            acc[ct] = __builtin_amdgcn_mfma_f32_16x16x32_f16(a, b, acc[ct], 0, 0, 0);
        }
    }

    const int rbase = row0 + kseg * 4;
#pragma unroll
    for (int ct = 0; ct < CT; ++ct)
#pragma unroll
        for (int r = 0; r < 4; ++r) {
            int row = rbase + r;
            if (row < N) H[(long)row * KOUT + ct * 16 + c] = (f16)acc[ct][r];
        }
}

// One wave per node; fp16 payloads, fp32 accumulate; 8/4/1 edge unroll.
template <int F, bool RELU, bool OUTF16>
__global__ __launch_bounds__(256) void gather_kernel(const void* __restrict__ Hv,
                                                     const int* __restrict__ rowptr,
                                                     const float2* __restrict__ pairs,
                                                     const float* __restrict__ dinv,
                                                     const float* __restrict__ bias,
                                                     void* __restrict__ outv, int N) {
    const int wid = threadIdx.x >> 6;
    const int lane = threadIdx.x & 63;
    const int node = blockIdx.x * 4 + wid;
    if (node >= N) return;
    const int start = rowptr[node], end = rowptr[node + 1];

    if (F == 128) {
        const __half2* Hu = (const __half2*)Hv;
        float ax = 0.f, ay = 0.f;
        int e = start;
        for (; e + 7 < end; e += 8) {
            float2 pp[8];
            __half2 uu[8];
#pragma unroll
            for (int j = 0; j < 8; ++j) pp[j] = pairs[e + j];
#pragma unroll
            for (int j = 0; j < 8; ++j) uu[j] = Hu[(long)__float_as_int(pp[j].x) * 64 + lane];
#pragma unroll
            for (int j = 0; j < 8; ++j) {
                float2 f = __half22float2(uu[j]);
                ax += f.x * pp[j].y;
                ay += f.y * pp[j].y;
            }
        }
        for (; e + 3 < end; e += 4) {
            float2 pp[4];
            __half2 uu[4];
#pragma unroll
            for (int j = 0; j < 4; ++j) pp[j] = pairs[e + j];
#pragma unroll
            for (int j = 0; j < 4; ++j) uu[j] = Hu[(long)__float_as_int(pp[j].x) * 64 + lane];
#pragma unroll
            for (int j = 0; j < 4; ++j) {
                float2 f = __half22float2(uu[j]);
                ax += f.x * pp[j].y;
                ay += f.y * pp[j].y;
            }
        }
        for (; e < end; ++e) {
            float2 p0 = pairs[e];
            float2 f0 = __half22float2(Hu[(long)__float_as_int(p0.x) * 64 + lane]);
            ax += f0.x * p0.y;
            ay += f0.y * p0.y;
        }
        float di = dinv[node];
        float d2 = di * di;
        float2 fs = __half22float2(Hu[(long)node * 64 + lane]);
        float2 bz = ((const float2*)bias)[lane];
        float zx = ax + fs.x * d2 + bz.x;
        float zy = ay + fs.y * d2 + bz.y;
        if (RELU) { zx = fmaxf(zx, 0.f); zy = fmaxf(zy, 0.f); }
        if (OUTF16) {
            ((__half2*)outv)[(long)node * 64 + lane] = __float22half2_rn(make_float2(zx, zy));
        } else {
            float2 o = {zx, zy};
            ((float2*)outv)[(long)node * 64 + lane] = o;
        }
    } else {  // F == 64
        const __half* Hh = (const __half*)Hv;
        float acc = 0.f;
        int e = start;
        for (; e + 7 < end; e += 8) {
            float2 pp[8];
            __half uu[8];
#pragma unroll
            for (int j = 0; j < 8; ++j) pp[j] = pairs[e + j];
#pragma unroll
            for (int j = 0; j < 8; ++j) uu[j] = Hh[(long)__float_as_int(pp[j].x) * 64 + lane];
#pragma unroll
            for (int j = 0; j < 8; ++j) acc += __half2float(uu[j]) * pp[j].y;
        }
        for (; e + 3 < end; e += 4) {
            float2 pp[4];
            __half uu[4];
#pragma unroll
            for (int j = 0; j < 4; ++j) pp[j] = pairs[e + j];
#pragma unroll
            for (int j = 0; j < 4; ++j) uu[j] = Hh[(long)__float_as_int(pp[j].x) * 64 + lane];
#pragma unroll
            for (int j = 0; j < 4; ++j) acc += __half2float(uu[j]) * pp[j].y;
        }
        for (; e < end; ++e) {
            float2 p0 = pairs[e];
            acc += __half2float(Hh[(long)__float_as_int(p0.x) * 64 + lane]) * p0.y;
        }
        float di = dinv[node];
        float z = acc + __half2float(Hh[(long)node * 64 + lane]) * (di * di) + bias[lane];
        if (RELU) z = fmaxf(z, 0.f);
        ((float*)outv)[(long)node * 64 + lane] = z;
    }
}

extern "C" void kernel_launch(void* const* d_in, const int* in_sizes, int n_in,
                              void* d_out, int out_size, void* d_ws, size_t ws_size,
                              hipStream_t stream) {
    const float* x  = (const float*)d_in[0];
    const int*   ei = (const int*)d_in[1];
    const float* W1 = (const float*)d_in[2];
    const float* b1 = (const float*)d_in[3];
    const float* W2 = (const float*)d_in[4];
    const float* b2 = (const float*)d_in[5];
    float* out = (float*)d_out;

    const int N = in_sizes[0] / 128;  // 50000
    const int E = in_sizes[1] / 2;    // 800000
    const int* src = ei;
    const int* dst = ei + E;
    const int NB = (N + 1023) / 1024;  // 49

    // workspace carving (float units; all 16B-aligned enough)
    float* ws = (float*)d_ws;
    float2* pairs = (float2*)ws;                  // [E]
    long off = 2L * E;
    int* posw   = (int*)(ws + off); off += E;
    int* deg    = (int*)(ws + off); off += N;
    int* rowptr = (int*)(ws + off); off += N + 1;
    int* bsum   = (int*)(ws + off); off += 64;
    float* dinv = ws + off;        off += N;
    off = (off + 3) & ~3L;
    f16* Wt1 = (f16*)(ws + off); off += (128 * 136) / 2;
    f16* Wt2 = (f16*)(ws + off); off += (64 * 136) / 2;
    f16* h1  = (f16*)(ws + off); off += (long)N * 64;   // N*128 fp16
    f16* z1  = (f16*)(ws + off); off += (long)N * 64;   // N*128 fp16
    f16* h2  = (f16*)(ws + off); off += (long)N * 32;   // N*64 fp16

    // --- CSR build (atomic pass 1 captures positions) ---
    hipMemsetAsync(deg, 0, (size_t)N * sizeof(int), stream);
    deg_prep_kernel<<<(E + 255) / 256, 256, 0, stream>>>(dst, deg, posw, W1, W2, Wt1, Wt2, E);
    scan1_kernel<<<NB, 1024, 0, stream>>>(deg, rowptr, bsum, dinv, N);
    scan23_kernel<<<NB, 1024, 0, stream>>>(rowptr, bsum, N, NB);
    fill_kernel<<<(E + 255) / 256, 256, 0, stream>>>(src, dst, posw, dinv, rowptr, pairs, E);

    // --- layer 1: h1 = f16(x@W1); z1 = f16(relu(agg + self + b1)) ---
    gemm_kernel<128, true><<<(N + 63) / 64, 256, 0, stream>>>(x, Wt1, h1, N);
    gather_kernel<128, true, true><<<(N + 3) / 4, 256, 0, stream>>>(h1, rowptr, pairs, dinv, b1, z1, N);

    // --- layer 2: h2 = f16(z1@W2); out = agg + self + b2 (fp32) ---
    gemm_kernel<64, false><<<(N + 63) / 64, 256, 0, stream>>>(z1, Wt2, h2, N);
    gather_kernel<64, false, false><<<(N + 3) / 4, 256, 0, stream>>>(h2, rowptr, pairs, dinv, b2, out, N);
}